// Round 1
// baseline (307.036 us; speedup 1.0000x reference)
//
#include <hip/hip_runtime.h>

// MFELoss: fused softmax(C=4) + masked-mean reduction to a scalar.
// Memory-bound: 128 MiB preds + 32 MiB target -> ~27 us floor @ 6.3 TB/s.

__global__ __launch_bounds__(256) void mfe_kernel(
    const float4* __restrict__ preds,   // B rows of 4 floats, float4-aligned
    const int* __restrict__ target,     // B ints
    const int* __restrict__ others_idx_p,
    float* __restrict__ out,
    unsigned char* __restrict__ ws,     // 32B: [0]fne_sum d, [8]fpe_sum d, [16]cnt u64, [24]ticket u32
    int n_rows)
{
    double* fne_sum = (double*)(ws + 0);
    double* fpe_sum = (double*)(ws + 8);
    unsigned long long* cnt_sum = (unsigned long long*)(ws + 16);
    unsigned int* ticket = (unsigned int*)(ws + 24);

    const int o = *others_idx_p;  // wave-uniform

    int idx = blockIdx.x * blockDim.x + threadIdx.x;
    int stride = gridDim.x * blockDim.x;

    float fne_acc = 0.0f;
    float fpe_acc = 0.0f;
    unsigned int cnt_acc = 0u;

    for (int i = idx; i < n_rows; i += stride) {
        float4 x = preds[i];
        int t = target[i];

        float m = fmaxf(fmaxf(x.x, x.y), fmaxf(x.z, x.w));
        float e0 = __expf(x.x - m);
        float e1 = __expf(x.y - m);
        float e2 = __expf(x.z - m);
        float e3 = __expf(x.w - m);
        float S = (e0 + e1) + (e2 + e3);
        float r = 1.0f / S;
        float p0 = e0 * r, p1 = e1 * r, p2 = e2 * r, p3 = e3 * r;
        float s = ((p0 + p1) + p2) + p3;             // ~1.0, computed faithfully
        float po = (o == 0) ? p0 : (o == 1) ? p1 : (o == 2) ? p2 : p3;

        float d1 = s - po;
        float d2 = po - 1.0f;
        float fne_i = 0.5f * (d1 * d1 + d2 * d2);
        float fpe_i = po * po;                        // 0.5*(po^2 + po^2)

        bool is_o = (t == o);
        fne_acc += is_o ? fne_i : 0.0f;
        fpe_acc += is_o ? 0.0f : fpe_i;
        cnt_acc += is_o ? 1u : 0u;
    }

    // 64-lane wave reduction
    #pragma unroll
    for (int off = 32; off > 0; off >>= 1) {
        fne_acc += __shfl_down(fne_acc, off, 64);
        fpe_acc += __shfl_down(fpe_acc, off, 64);
        cnt_acc += __shfl_down(cnt_acc, off, 64);
    }

    __shared__ float s_fne[4], s_fpe[4];
    __shared__ unsigned int s_cnt[4];
    int wave = threadIdx.x >> 6;
    int lane = threadIdx.x & 63;
    if (lane == 0) { s_fne[wave] = fne_acc; s_fpe[wave] = fpe_acc; s_cnt[wave] = cnt_acc; }
    __syncthreads();

    if (threadIdx.x == 0) {
        float bf = (s_fne[0] + s_fne[1]) + (s_fne[2] + s_fne[3]);
        float bp = (s_fpe[0] + s_fpe[1]) + (s_fpe[2] + s_fpe[3]);
        unsigned int bc = (s_cnt[0] + s_cnt[1]) + (s_cnt[2] + s_cnt[3]);

        atomicAdd(fne_sum, (double)bf);
        atomicAdd(fpe_sum, (double)bp);
        atomicAdd(cnt_sum, (unsigned long long)bc);
        __threadfence();  // make sums visible before taking a ticket

        unsigned int tk = atomicAdd(ticket, 1u);
        if (tk == gridDim.x - 1) {
            // last block: all other blocks' atomics are done & visible
            __threadfence();
            double fn = atomicAdd(fne_sum, 0.0);            // atomic read (coherent)
            double fp = atomicAdd(fpe_sum, 0.0);
            unsigned long long c = atomicAdd(cnt_sum, 0ull);
            double fne_num = (double)c;
            double fpe_num = (double)n_rows - fne_num;
            double res = 0.0;
            if (fpe_num > 0.0) res += fp / fpe_num;
            if (fne_num > 0.0) res += fn / fne_num;
            out[0] = (float)res;
        }
    }
}

extern "C" void kernel_launch(void* const* d_in, const int* in_sizes, int n_in,
                              void* d_out, int out_size, void* d_ws, size_t ws_size,
                              hipStream_t stream) {
    const float4* preds = (const float4*)d_in[0];
    const int* target = (const int*)d_in[1];
    const int* others_idx = (const int*)d_in[2];
    float* out = (float*)d_out;

    int n_rows = in_sizes[0] / 4;   // B = 8388608

    // zero the 32-byte accumulator block in workspace (poisoned 0xAA otherwise)
    hipMemsetAsync(d_ws, 0, 32, stream);

    const int block = 256;
    const int grid = 2048;          // 8 blocks/CU; ~16 rows/thread grid-stride
    mfe_kernel<<<grid, block, 0, stream>>>(preds, target, others_idx, out,
                                           (unsigned char*)d_ws, n_rows);
}

// Round 2
// 219.728 us; speedup vs baseline: 1.3973x; 1.3973x over previous
//
#include <hip/hip_runtime.h>

// MFELoss: fused softmax(C=4) + masked-mean reduction to a scalar.
// R2: 8 rows/thread fully unrolled (16 loads in flight) + atomic-free
// two-stage reduction (per-block partials in d_ws, tiny finalize kernel).

#define BLOCK 256
#define ROWS 8

__device__ __forceinline__ void mfe_row(float4 x, int t, int o,
                                        float& fne_acc, float& fpe_acc,
                                        unsigned int& cnt_acc) {
    float m = fmaxf(fmaxf(x.x, x.y), fmaxf(x.z, x.w));
    float e0 = __expf(x.x - m);
    float e1 = __expf(x.y - m);
    float e2 = __expf(x.z - m);
    float e3 = __expf(x.w - m);
    float S = (e0 + e1) + (e2 + e3);
    float r = 1.0f / S;
    float p0 = e0 * r, p1 = e1 * r, p2 = e2 * r, p3 = e3 * r;
    float s = ((p0 + p1) + p2) + p3;          // ~1.0, computed faithfully
    float po = (o == 0) ? p0 : (o == 1) ? p1 : (o == 2) ? p2 : p3;

    float d1 = s - po;
    float d2 = po - 1.0f;
    float fne_i = 0.5f * (d1 * d1 + d2 * d2);
    float fpe_i = po * po;                    // 0.5*(po^2+po^2)

    bool is_o = (t == o);
    fne_acc += is_o ? fne_i : 0.0f;
    fpe_acc += is_o ? 0.0f : fpe_i;
    cnt_acc += is_o ? 1u : 0u;
}

__global__ __launch_bounds__(BLOCK) void mfe_partial(
    const float4* __restrict__ preds,
    const int* __restrict__ target,
    const int* __restrict__ others_idx_p,
    float* __restrict__ fne_part,
    float* __restrict__ fpe_part,
    unsigned int* __restrict__ cnt_part,
    int n_rows)
{
    const int o = *others_idx_p;  // wave-uniform scalar
    int tid = blockIdx.x * blockDim.x + threadIdx.x;
    int nth = gridDim.x * blockDim.x;

    float fne_acc = 0.0f, fpe_acc = 0.0f;
    unsigned int cnt_acc = 0u;

    if (tid + (ROWS - 1) * nth < n_rows) {
        // fast path: issue all 16 loads before any use -> deep MLP
        float4 x[ROWS];
        int    t[ROWS];
        #pragma unroll
        for (int k = 0; k < ROWS; ++k) x[k] = preds[tid + k * nth];
        #pragma unroll
        for (int k = 0; k < ROWS; ++k) t[k] = target[tid + k * nth];
        #pragma unroll
        for (int k = 0; k < ROWS; ++k)
            mfe_row(x[k], t[k], o, fne_acc, fpe_acc, cnt_acc);
    } else {
        for (int i = tid; i < n_rows; i += nth)
            mfe_row(preds[i], target[i], o, fne_acc, fpe_acc, cnt_acc);
    }

    // 64-lane wave reduction
    #pragma unroll
    for (int off = 32; off > 0; off >>= 1) {
        fne_acc += __shfl_down(fne_acc, off, 64);
        fpe_acc += __shfl_down(fpe_acc, off, 64);
        cnt_acc += __shfl_down(cnt_acc, off, 64);
    }

    __shared__ float s_fne[BLOCK / 64], s_fpe[BLOCK / 64];
    __shared__ unsigned int s_cnt[BLOCK / 64];
    int wave = threadIdx.x >> 6;
    int lane = threadIdx.x & 63;
    if (lane == 0) { s_fne[wave] = fne_acc; s_fpe[wave] = fpe_acc; s_cnt[wave] = cnt_acc; }
    __syncthreads();

    if (threadIdx.x == 0) {
        float bf = 0.0f, bp = 0.0f; unsigned int bc = 0u;
        #pragma unroll
        for (int w = 0; w < BLOCK / 64; ++w) { bf += s_fne[w]; bp += s_fpe[w]; bc += s_cnt[w]; }
        fne_part[blockIdx.x] = bf;
        fpe_part[blockIdx.x] = bp;
        cnt_part[blockIdx.x] = bc;
    }
}

__global__ __launch_bounds__(1024) void mfe_final(
    const float* __restrict__ fne_part,
    const float* __restrict__ fpe_part,
    const unsigned int* __restrict__ cnt_part,
    int nparts, int n_rows, float* __restrict__ out)
{
    double fn = 0.0, fp = 0.0;
    unsigned long long c = 0ull;
    for (int i = threadIdx.x; i < nparts; i += blockDim.x) {
        fn += (double)fne_part[i];
        fp += (double)fpe_part[i];
        c  += (unsigned long long)cnt_part[i];
    }
    #pragma unroll
    for (int off = 32; off > 0; off >>= 1) {
        fn += __shfl_down(fn, off, 64);
        fp += __shfl_down(fp, off, 64);
        c  += __shfl_down(c, off, 64);
    }
    __shared__ double s_fn[16], s_fp[16];
    __shared__ unsigned long long s_c[16];
    int wave = threadIdx.x >> 6;
    int lane = threadIdx.x & 63;
    if (lane == 0) { s_fn[wave] = fn; s_fp[wave] = fp; s_c[wave] = c; }
    __syncthreads();

    if (threadIdx.x == 0) {
        double tfn = 0.0, tfp = 0.0;
        unsigned long long tc = 0ull;
        int nwaves = blockDim.x >> 6;
        for (int w = 0; w < nwaves; ++w) { tfn += s_fn[w]; tfp += s_fp[w]; tc += s_c[w]; }
        double fne_num = (double)tc;
        double fpe_num = (double)n_rows - fne_num;
        double res = 0.0;
        if (fpe_num > 0.0) res += tfp / fpe_num;
        if (fne_num > 0.0) res += tfn / fne_num;
        out[0] = (float)res;
    }
}

extern "C" void kernel_launch(void* const* d_in, const int* in_sizes, int n_in,
                              void* d_out, int out_size, void* d_ws, size_t ws_size,
                              hipStream_t stream) {
    const float4* preds = (const float4*)d_in[0];
    const int* target = (const int*)d_in[1];
    const int* others_idx = (const int*)d_in[2];
    float* out = (float*)d_out;

    int n_rows = in_sizes[0] / 4;   // B = 8388608

    int grid = (n_rows + BLOCK * ROWS - 1) / (BLOCK * ROWS);  // 4096 for B=2^23

    // workspace layout: [fne_part grid floats][fpe_part grid floats][cnt_part grid uints]
    float* fne_part = (float*)d_ws;
    float* fpe_part = fne_part + grid;
    unsigned int* cnt_part = (unsigned int*)(fpe_part + grid);

    mfe_partial<<<grid, BLOCK, 0, stream>>>(preds, target, others_idx,
                                            fne_part, fpe_part, cnt_part, n_rows);
    mfe_final<<<1, 1024, 0, stream>>>(fne_part, fpe_part, cnt_part,
                                      grid, n_rows, out);
}